// Round 4
// baseline (257.841 us; speedup 1.0000x reference)
//
#include <hip/hip_runtime.h>

// Fused RK4 step, 2D Burgers-like PDE, periodic BCs, radius-2 cross stencils.
// Tile 64x64 output, 80x80 staged. R4: register-resident 5-row x 4-col strips
// per thread (320 threads = 16 rowgroups x 20 colquads); vertical neighbors
// from registers, only horizontal +-2 and 4 halo rows from LDS. Full-region
// compute (garbage ring shrinks away; validated in R1). No act guards.

typedef float f4 __attribute__((ext_vector_type(4)));
typedef float f2 __attribute__((ext_vector_type(2)));

#define LCOLS 88            // 4 pad + 80 + 4 pad floats
#define LROWS 84            // 2 pad + 80 + 2 pad rows
#define NBUF  (LROWS*LCOLS) // 7392 floats = 29568 B per field
#define NT    320           // 5 waves; 16 rowgroups x 20 colquads

__global__ __launch_bounds__(NT, 2)
void rk4_stencil(const float* __restrict__ h,
                 const float* __restrict__ sRe, const float* __restrict__ sUA,
                 const float* __restrict__ sUB, const float* __restrict__ sVA,
                 const float* __restrict__ sVB, float* __restrict__ out)
{
    __shared__ __align__(16) float tu[NBUF];
    __shared__ __align__(16) float tv[NBUF];

    const int tid = threadIdx.x;
    const int tc = blockIdx.x, tr = blockIdx.y, bb = blockIdx.z;

    const float Re = sRe[0], UA = sUA[0], UB = sUB[0], VA = sVA[0], VB = sVB[0];
    const float nu = 0.001f / Re;

    const float d1 = 800.f/12.f;          // (8/12)/DX
    const float d2 = 100.f/12.f;          // (1/12)/DX
    const float a1 = (4.f/3.f)*1.0e4f;    // (4/3)/DX^2
    const float a2 = -(1.f/12.f)*1.0e4f;  // (-1/12)/DX^2
    const float a0 = -5.0e4f;             // -5/DX^2 (both axes center)

    const f4 z4 = {0.f, 0.f, 0.f, 0.f};

    // zero both buffers (pads must be zero; interior overwritten by staging)
    for (int i = tid; i < NBUF/4; i += NT) { ((f4*)tu)[i] = z4; ((f4*)tv)[i] = z4; }
    __syncthreads();

    const size_t plane = 1048576;
    const float* uin = h + (size_t)(bb*2) * plane;
    const float* vin = uin + plane;
    const int base_r = tr*64 - 8, base_c = tc*64 - 8;

    // stage 80x80 (= 1600 f4 per field = exactly 5 per thread), wrap indexing
#pragma unroll
    for (int m = 0; m < 5; ++m) {
        int g = tid + NT*m;
        int r = g / 20, k = g - r*20;
        int gr = (base_r + r) & 1023;
        int gc = (base_c + 4*k) & 1023;
        int l = (r+2)*LCOLS + 4 + 4*k;
        *(f4*)(tu + l) = *(const f4*)(uin + (size_t)gr*1024 + gc);
        *(f4*)(tv + l) = *(const f4*)(vin + (size_t)gr*1024 + gc);
    }
    __syncthreads();

    // strip ownership: colquad c (cells 4c..4c+3), rows rg*5 .. rg*5+4
    const int c  = tid % 20;
    const int rg = tid / 20;
    const int l0 = (rg*5 + 2)*LCOLS + 4 + 4*c;

    f4 u0s[5], v0s[5], us[5], vs[5], au[5], av[5];
#pragma unroll
    for (int k = 0; k < 5; ++k) {
        u0s[k] = *(const f4*)(tu + l0 + k*LCOLS);
        v0s[k] = *(const f4*)(tv + l0 + k*LCOLS);
        us[k] = u0s[k]; vs[k] = v0s[k];
        au[k] = z4; av[k] = z4;
    }

    float* outu = out + (size_t)(bb*2) * plane;
    float* outv = outu + plane;
    const bool col_ok = (c >= 2 && c < 18);

#pragma unroll
    for (int s = 0; s < 4; ++s) {
        const float wgt  = (s == 1 || s == 2) ? 2.f : 1.f;
        const float cadd = (s <= 1) ? 0.25f : 0.5f;     // DT/2, DT/2, DT

        // vertical halo rows (outside the strip), 4 per field
        f4 t2u = *(const f4*)(tu + l0 - 2*LCOLS);
        f4 t1u = *(const f4*)(tu + l0 - 1*LCOLS);
        f4 b1u = *(const f4*)(tu + l0 + 5*LCOLS);
        f4 b2u = *(const f4*)(tu + l0 + 6*LCOLS);
        f4 t2v = *(const f4*)(tv + l0 - 2*LCOLS);
        f4 t1v = *(const f4*)(tv + l0 - 1*LCOLS);
        f4 b1v = *(const f4*)(tv + l0 + 5*LCOLS);
        f4 b2v = *(const f4*)(tv + l0 + 6*LCOLS);

        f4 nus[5], nvs[5];
#pragma unroll
        for (int k = 0; k < 5; ++k) {
            const int lk = l0 + k*LCOLS;
            f2 ulf = *(const f2*)(tu + lk - 2);
            f2 urf = *(const f2*)(tu + lk + 4);
            f2 vlf = *(const f2*)(tv + lk - 2);
            f2 vrf = *(const f2*)(tv + lk + 4);

            f4 un1 = (k >= 1) ? us[k-1] : t1u;
            f4 un2 = (k >= 2) ? us[k-2] : ((k == 1) ? t1u : t2u);
            f4 uS1 = (k <= 3) ? us[k+1] : b1u;
            f4 uS2 = (k <= 2) ? us[k+2] : ((k == 3) ? b1u : b2u);
            f4 vn1 = (k >= 1) ? vs[k-1] : t1v;
            f4 vn2 = (k >= 2) ? vs[k-2] : ((k == 1) ? t1v : t2v);
            f4 vS1 = (k <= 3) ? vs[k+1] : b1v;
            f4 vS2 = (k <= 2) ? vs[k+2] : ((k == 3) ? b1v : b2v);

            f4 uc = us[k], vc = vs[k];
            float hu[8] = {ulf[0],ulf[1],uc[0],uc[1],uc[2],uc[3],urf[0],urf[1]};
            float hv[8] = {vlf[0],vlf[1],vc[0],vc[1],vc[2],vc[3],vrf[0],vrf[1]};

            f4 fu4, fv4;
#pragma unroll
            for (int j = 0; j < 4; ++j) {
                float u = hu[j+2], v = hv[j+2];
                // row-direction derivative (axis 2) = reference K_DX
                float urow = d1*(uS1[j]-un1[j]) + d2*(un2[j]-uS2[j]);
                float vrow = d1*(vS1[j]-vn1[j]) + d2*(vn2[j]-vS2[j]);
                // col-direction derivative (axis 3) = reference K_DY
                float ucol = d1*(hu[j+3]-hu[j+1]) + d2*(hu[j]-hu[j+4]);
                float vcol = d1*(hv[j+3]-hv[j+1]) + d2*(hv[j]-hv[j+4]);
                float ulap = a1*((un1[j]+uS1[j])+(hu[j+1]+hu[j+3]))
                           + a2*((un2[j]+uS2[j])+(hu[j]+hu[j+4])) + a0*u;
                float vlap = a1*((vn1[j]+vS1[j])+(hv[j+1]+hv[j+3]))
                           + a2*((vn2[j]+vS2[j])+(hv[j]+hv[j+4])) + a0*v;
                fu4[j] = nu*ulap + UA*(u*urow) + UB*(v*ucol);
                fv4[j] = nu*vlap + VA*(u*vrow) + VB*(v*vcol);
            }

            if (s < 3) {
#pragma unroll
                for (int j = 0; j < 4; ++j) {
                    au[k][j] += wgt*fu4[j];
                    av[k][j] += wgt*fv4[j];
                    nus[k][j] = u0s[k][j] + cadd*fu4[j];
                    nvs[k][j] = v0s[k][j] + cadd*fv4[j];
                }
            } else {
                int r_st = rg*5 + k;
                if (col_ok && r_st >= 8 && r_st < 72) {
                    int gr = tr*64 + r_st - 8;
                    int gc = tc*64 + 4*c - 8;
                    f4 ou, ov;
#pragma unroll
                    for (int j = 0; j < 4; ++j) {
                        ou[j] = u0s[k][j] + (1.f/12.f)*(au[k][j] + fu4[j]);
                        ov[j] = v0s[k][j] + (1.f/12.f)*(av[k][j] + fv4[j]);
                    }
                    __builtin_nontemporal_store(ou, (f4*)(outu + (size_t)gr*1024 + gc));
                    __builtin_nontemporal_store(ov, (f4*)(outv + (size_t)gr*1024 + gc));
                }
            }
        }

        if (s < 3) {
            __syncthreads();   // all reads of t_s complete
#pragma unroll
            for (int k = 0; k < 5; ++k) {
                *(f4*)(tu + l0 + k*LCOLS) = nus[k];
                *(f4*)(tv + l0 + k*LCOLS) = nvs[k];
                us[k] = nus[k]; vs[k] = nvs[k];
            }
            __syncthreads();   // t_{s+1} visible
        }
    }
}

extern "C" void kernel_launch(void* const* d_in, const int* in_sizes, int n_in,
                              void* d_out, int out_size, void* d_ws, size_t ws_size,
                              hipStream_t stream) {
    const float* h   = (const float*)d_in[0];
    const float* sRe = (const float*)d_in[1];
    const float* sUA = (const float*)d_in[2];
    const float* sUB = (const float*)d_in[3];
    const float* sVA = (const float*)d_in[4];
    const float* sVB = (const float*)d_in[5];
    float* o = (float*)d_out;
    rk4_stencil<<<dim3(16,16,8), dim3(NT,1,1), 0, stream>>>(h, sRe, sUA, sUB, sVA, sVB, o);
}

// Round 5
// 235.583 us; speedup vs baseline: 1.0945x; 1.0945x over previous
//
#include <hip/hip_runtime.h>

// Fused RK4 step, 2D Burgers-like PDE, periodic BCs, radius-2 cross stencils.
// Tile 64x64 output, 80x80 staged in one in-place LDS buffer per field.
// R5: 2-row register strips (800 strips = 40 rowpairs x 20 colquads, NT=832).
// Persistent regs per thread: us,vs,ku,kv,au,av = 12 f4 = 48 VGPR (u0
// reconstructed from kprev, the R3 trick that compiled to 60 VGPR).
// Vertical/center neighbors from regs; only 4 halo rows + horiz +-2 from LDS.
// No pad zeroing, no region guards: garbage only contaminates the ring that
// shrinks away (2 cells/stage), output reads rows/cols [8,72) only.

typedef float f4 __attribute__((ext_vector_type(4)));
typedef float f2 __attribute__((ext_vector_type(2)));

#define LCOLS 88            // 4 pad + 80 + 4 pad floats
#define LROWS 84            // 2 pad + 80 + 2 pad rows
#define NBUF  (LROWS*LCOLS) // 7392 floats = 29568 B per field
#define NT    832           // 13 waves; strips: 40 rowpairs x 20 colquads = 800

__global__ __launch_bounds__(NT, 4)   // cap VGPR at 128: 13-wave block needs 4 w/SIMD
void rk4_stencil(const float* __restrict__ h,
                 const float* __restrict__ sRe, const float* __restrict__ sUA,
                 const float* __restrict__ sUB, const float* __restrict__ sVA,
                 const float* __restrict__ sVB, float* __restrict__ out)
{
    __shared__ __align__(16) float tu[NBUF];
    __shared__ __align__(16) float tv[NBUF];

    const int tid = threadIdx.x;
    const int tc = blockIdx.x, tr = blockIdx.y, bb = blockIdx.z;

    const float Re = sRe[0], UA = sUA[0], UB = sUB[0], VA = sVA[0], VB = sVB[0];
    const float nu = 0.001f / Re;

    const float d1 = 800.f/12.f;          // (8/12)/DX
    const float d2 = 100.f/12.f;          // (1/12)/DX
    const float a1 = (4.f/3.f)*1.0e4f;    // (4/3)/DX^2
    const float a2 = -(1.f/12.f)*1.0e4f;  // (-1/12)/DX^2
    const float a0 = -5.0e4f;             // -5/DX^2 (both axes center)

    const size_t plane = 1048576;
    const float* uin = h + (size_t)(bb*2) * plane;
    const float* vin = uin + plane;
    const int base_r = tr*64 - 8, base_c = tc*64 - 8;

    // stage 80x80 per field (1600 f4 groups), wrap indexing; no zeroing needed
#pragma unroll
    for (int m = 0; m < 2; ++m) {
        int gidx = tid + NT*m;
        if (gidx < 1600) {
            int r = gidx / 20, k = gidx - r*20;
            int gr = (base_r + r) & 1023;
            int gc = (base_c + 4*k) & 1023;
            int l = (r+2)*LCOLS + 4 + 4*k;
            *(f4*)(tu + l) = *(const f4*)(uin + (size_t)gr*1024 + gc);
            *(f4*)(tv + l) = *(const f4*)(vin + (size_t)gr*1024 + gc);
        }
    }
    __syncthreads();

    const bool active = tid < 800;
    const int c = tid % 20;          // colquad: cells 4c..4c+3
    const int g = tid / 20;          // rowpair: staged rows 2g, 2g+1
    const int l0 = (2*g + 2)*LCOLS + 4 + 4*c;

    const f4 z4 = {0.f, 0.f, 0.f, 0.f};
    f4 us0=z4, us1=z4, vs0=z4, vs1=z4;           // current t rows (regs)
    f4 ku0=z4, ku1=z4, kv0=z4, kv1=z4;           // previous-stage k
    f4 au0=z4, au1=z4, av0=z4, av1=z4;           // RK accumulator
    if (active) {
        us0 = *(const f4*)(tu + l0);
        us1 = *(const f4*)(tu + l0 + LCOLS);
        vs0 = *(const f4*)(tv + l0);
        vs1 = *(const f4*)(tv + l0 + LCOLS);
    }

    float* outu = out + (size_t)(bb*2) * plane;
    float* outv = outu + plane;

    // per-row stencil: vertical neighbors passed in; horizontal read here
    auto stencil = [&](const f4 uc, const f4 un1, const f4 un2, const f4 uS1, const f4 uS2,
                       const float* urow,
                       const f4 vc, const f4 vn1, const f4 vn2, const f4 vS1, const f4 vS2,
                       const float* vrow,
                       f4& fu, f4& fv) {
        f2 ulf = *(const f2*)(urow - 2);
        f2 urf = *(const f2*)(urow + 4);
        f2 vlf = *(const f2*)(vrow - 2);
        f2 vrf = *(const f2*)(vrow + 4);
        float hu[8] = {ulf[0],ulf[1],uc[0],uc[1],uc[2],uc[3],urf[0],urf[1]};
        float hv[8] = {vlf[0],vlf[1],vc[0],vc[1],vc[2],vc[3],vrf[0],vrf[1]};
#pragma unroll
        for (int j = 0; j < 4; ++j) {
            float u = hu[j+2], v = hv[j+2];
            // row-direction derivative (axis 2) = reference K_DX
            float udr = d1*(uS1[j]-un1[j]) + d2*(un2[j]-uS2[j]);
            float vdr = d1*(vS1[j]-vn1[j]) + d2*(vn2[j]-vS2[j]);
            // col-direction derivative (axis 3) = reference K_DY
            float udc = d1*(hu[j+3]-hu[j+1]) + d2*(hu[j]-hu[j+4]);
            float vdc = d1*(hv[j+3]-hv[j+1]) + d2*(hv[j]-hv[j+4]);
            float ulap = a1*((un1[j]+uS1[j])+(hu[j+1]+hu[j+3]))
                       + a2*((un2[j]+uS2[j])+(hu[j]+hu[j+4])) + a0*u;
            float vlap = a1*((vn1[j]+vS1[j])+(hv[j+1]+hv[j+3]))
                       + a2*((vn2[j]+vS2[j])+(hv[j]+hv[j+4])) + a0*v;
            fu[j] = nu*ulap + UA*(u*udr) + UB*(v*udc);
            fv[j] = nu*vlap + VA*(u*vdr) + VB*(v*vdc);
        }
    };

    const float csub_t[4] = {0.f, 0.25f, 0.25f, 0.5f};  // undo prev stage's update
    const float cadd_t[4] = {0.25f, 0.25f, 0.5f, 0.f};  // apply this stage's update
    const float wgt_t[4]  = {1.f, 2.f, 2.f, 1.f};

#pragma unroll
    for (int s = 0; s < 4; ++s) {
        if (active) {
            const float csub = csub_t[s], cadd = cadd_t[s], wgt = wgt_t[s];
            // vertical halo rows from LDS (rows 2g-2, 2g-1, 2g+2, 2g+3)
            f4 um2 = *(const f4*)(tu + l0 - 2*LCOLS);
            f4 um1 = *(const f4*)(tu + l0 - 1*LCOLS);
            f4 up1 = *(const f4*)(tu + l0 + 2*LCOLS);
            f4 up2 = *(const f4*)(tu + l0 + 3*LCOLS);
            f4 vm2 = *(const f4*)(tv + l0 - 2*LCOLS);
            f4 vm1 = *(const f4*)(tv + l0 - 1*LCOLS);
            f4 vp1 = *(const f4*)(tv + l0 + 2*LCOLS);
            f4 vp2 = *(const f4*)(tv + l0 + 3*LCOLS);

            f4 fu0, fv0, fu1, fv1;
            stencil(us0, um1, um2, us1, up1, tu + l0,
                    vs0, vm1, vm2, vs1, vp1, tv + l0, fu0, fv0);
            stencil(us1, us0, um1, up1, up2, tu + l0 + LCOLS,
                    vs1, vs0, vm1, vp1, vp2, tv + l0 + LCOLS, fu1, fv1);

            if (s < 3) {
#pragma unroll
                for (int j = 0; j < 4; ++j) {
                    au0[j] += wgt*fu0[j];  av0[j] += wgt*fv0[j];
                    au1[j] += wgt*fu1[j];  av1[j] += wgt*fv1[j];
                    // t_{s+1} = u0 + cadd*k_new, u0 = t_s - csub*k_prev
                    us0[j] = (us0[j] - csub*ku0[j]) + cadd*fu0[j];
                    vs0[j] = (vs0[j] - csub*kv0[j]) + cadd*fv0[j];
                    us1[j] = (us1[j] - csub*ku1[j]) + cadd*fu1[j];
                    vs1[j] = (vs1[j] - csub*kv1[j]) + cadd*fv1[j];
                }
                ku0 = fu0; kv0 = fv0; ku1 = fu1; kv1 = fv1;
            } else if (g >= 4 && g < 36 && c >= 2 && c < 18) {
                // out = u0 + (1/12)*(k1+2k2+2k3+k4), u0 = t3 - DT*k3
                int gr = tr*64 + 2*g - 8;
                int gc = tc*64 + 4*c - 8;
                f4 o;
#pragma unroll
                for (int j = 0; j < 4; ++j) o[j] = (us0[j] - 0.5f*ku0[j]) + (1.f/12.f)*(au0[j] + fu0[j]);
                __builtin_nontemporal_store(o, (f4*)(outu + (size_t)gr*1024 + gc));
#pragma unroll
                for (int j = 0; j < 4; ++j) o[j] = (vs0[j] - 0.5f*kv0[j]) + (1.f/12.f)*(av0[j] + fv0[j]);
                __builtin_nontemporal_store(o, (f4*)(outv + (size_t)gr*1024 + gc));
#pragma unroll
                for (int j = 0; j < 4; ++j) o[j] = (us1[j] - 0.5f*ku1[j]) + (1.f/12.f)*(au1[j] + fu1[j]);
                __builtin_nontemporal_store(o, (f4*)(outu + (size_t)(gr+1)*1024 + gc));
#pragma unroll
                for (int j = 0; j < 4; ++j) o[j] = (vs1[j] - 0.5f*kv1[j]) + (1.f/12.f)*(av1[j] + fv1[j]);
                __builtin_nontemporal_store(o, (f4*)(outv + (size_t)(gr+1)*1024 + gc));
            }
        }
        if (s < 3) {
            __syncthreads();   // all reads of t_s complete
            if (active) {
                *(f4*)(tu + l0)         = us0;
                *(f4*)(tu + l0 + LCOLS) = us1;
                *(f4*)(tv + l0)         = vs0;
                *(f4*)(tv + l0 + LCOLS) = vs1;
            }
            __syncthreads();   // t_{s+1} visible
        }
    }
}

extern "C" void kernel_launch(void* const* d_in, const int* in_sizes, int n_in,
                              void* d_out, int out_size, void* d_ws, size_t ws_size,
                              hipStream_t stream) {
    const float* h   = (const float*)d_in[0];
    const float* sRe = (const float*)d_in[1];
    const float* sUA = (const float*)d_in[2];
    const float* sUB = (const float*)d_in[3];
    const float* sVA = (const float*)d_in[4];
    const float* sVB = (const float*)d_in[5];
    float* o = (float*)d_out;
    rk4_stencil<<<dim3(16,16,8), dim3(NT,1,1), 0, stream>>>(h, sRe, sUA, sUB, sVA, sVB, o);
}